// Round 13
// baseline (149.622 us; speedup 1.0000x reference)
//
#include <hip/hip_runtime.h>
#include <hip/hip_bf16.h>
#include <math.h>

#define N_SAMP 32768
#define NPAIR  (N_SAMP/2)
#define NBLK   768                 // 3 blocks/CU -> reg headroom (R5 lesson)

typedef short bf16x8 __attribute__((ext_vector_type(8)));
typedef float f32x4  __attribute__((ext_vector_type(4)));

__device__ __forceinline__ float dot4(const float4& a, const float4& b) {
    return a.x*b.x + a.y*b.y + a.z*b.z + a.w*b.w;
}
__device__ __forceinline__ ushort f2bfu(float x) {
    __hip_bfloat16 h = __float2bfloat16(x);
    ushort u; __builtin_memcpy(&u, &h, 2); return u;
}
__device__ __forceinline__ unsigned int pk2bf(float x, float y) {
    return (unsigned int)f2bfu(x) | ((unsigned int)f2bfu(y) << 16);
}
__device__ __forceinline__ float bflo(unsigned int q) { return __uint_as_float(q << 16); }
__device__ __forceinline__ float bfhi(unsigned int q) { return __uint_as_float(q & 0xffff0000u); }
__device__ __forceinline__ void gfadd(float* p, float v) {
    __hip_atomic_fetch_add(p, v, __ATOMIC_RELAXED, __HIP_MEMORY_SCOPE_AGENT);
}

// ---------------- main kernel ----------------
// R12 + early prefetch (R13): prefetch issued right after staging, so its
// in-flight time spans the WHOLE iteration (MFMA+inv+colsum+loss ~ full HBM
// latency), not just the loss phase. Enabled register-neutrally by sourcing
// colsum from the just-staged bf16 LDS (16 ds_read_b64 at each lane's own
// written address) into the SAME row-layout colacc[8] -- v[] dies at stage
// time and is purely the in-flight buffer (R8's +32-reg mistake avoided).
// Lessons: R6 unconditional prefetch; R9 NT loads win ~19us; R11 no peel.

template<bool ATOMIC>
__global__ __launch_bounds__(256, 3) void nssd_main(const float* __restrict__ gf,
                                                    const float* __restrict__ cc,
                                                    float* __restrict__ ws,
                                                    int nblk)
{
    __shared__ unsigned int lds_stage[4][2048];  // 32 KB: per-wave staging; epilogue colsum
    __shared__ unsigned int lds_ccn[1024];       // 4 KB: ccn bf16 [8][256] XOR-swizzled
    __shared__ float lds_red[8];

    const int tid  = threadIdx.x;
    const int lane = tid & 63;
    const int w    = tid >> 6;

    // ---- normalize cluster_center (f32 tmp in lds_stage) ----
    {
        float* cptr = (float*)lds_stage;
        const int l32 = tid & 31, st = tid >> 5;
        const float4* cc4 = (const float4*)cc;
        float4 a = cc4[st*64 + l32];
        float4 b = cc4[st*64 + 32 + l32];
        float ss = dot4(a,a) + dot4(b,b);
        #pragma unroll
        for (int m = 1; m < 32; m <<= 1) ss += __shfl_xor(ss, m);
        float inv = 1.0f / (sqrtf(ss) + 1e-12f);
        *(float4*)(cptr + st*256 + l32*4)       = make_float4(a.x*inv,a.y*inv,a.z*inv,a.w*inv);
        *(float4*)(cptr + st*256 + 128 + l32*4) = make_float4(b.x*inv,b.y*inv,b.z*inv,b.w*inv);
    }
    __syncthreads();
    // ---- ccn -> bf16 LDS, swizzled: byte = row*512 + ((col*2) ^ (row<<4)) ----
    {
        const float* cptr = (const float*)lds_stage;
        int row = tid >> 5, c0 = (tid & 31) * 8;
        uint4 uu;
        uu.x = pk2bf(cptr[row*256+c0+0], cptr[row*256+c0+1]);
        uu.y = pk2bf(cptr[row*256+c0+2], cptr[row*256+c0+3]);
        uu.z = pk2bf(cptr[row*256+c0+4], cptr[row*256+c0+5]);
        uu.w = pk2bf(cptr[row*256+c0+6], cptr[row*256+c0+7]);
        *(uint4*)((char*)lds_ccn + row*512 + ((c0*2) ^ (row << 4))) = uu;
    }
    __syncthreads();

    char* sbase = (char*)lds_stage + w*8192;
    char* cbase = (char*)lds_ccn;
    const int G = lane >> 4, C = lane & 15;
    const int Ck = (C & 7) << 4;

    f32x4 colacc[8];
    #pragma unroll
    for (int s = 0; s < 8; ++s) colacc[s] = (f32x4){0.f,0.f,0.f,0.f};
    float l1 = 0.f, l2 = 0.f;

    const int stride = nblk*4;
    int p = blockIdx.x*4 + w;          // always < NPAIR at start (3072 <= 16384)

    // ---- prologue: issue first tile's loads (unconditional) ----
    f32x4 v[16];
    {
        const f32x4* g4 = (const f32x4*)(gf + (size_t)p * 4096);
        #pragma unroll
        for (int i = 0; i < 16; ++i)
            v[i] = __builtin_nontemporal_load(g4 + i*64 + lane);
    }

    for (; p < NPAIR; p += stride) {
        // ---- convert + stage (swizzled); v DIES here ----
        #pragma unroll
        for (int i = 0; i < 16; ++i) {
            uint2 uu = make_uint2(pk2bf(v[i][0], v[i][1]), pk2bf(v[i][2], v[i][3]));
            *(uint2*)(sbase + i*512 + ((lane*8) ^ ((i & 7) << 4))) = uu;
        }

        // ---- issue NEXT tile's loads NOW (in-flight across whole body) ----
        {
            int pn = p + stride;
            size_t pa = (size_t)(pn < NPAIR ? pn : 0) * 4096;
            const f32x4* g4 = (const f32x4*)(gf + pa);
            #pragma unroll
            for (int i = 0; i < 16; ++i)
                v[i] = __builtin_nontemporal_load(g4 + i*64 + lane);
        }
        __builtin_amdgcn_sched_barrier(0);   // pin issue point (don't sink)

        // ---- MFMA: Gram (u,u) and E (u,ccn), K=256 in 8 steps ----
        f32x4 accg = (f32x4){0.f,0.f,0.f,0.f};
        f32x4 acce = (f32x4){0.f,0.f,0.f,0.f};
        #pragma unroll
        for (int kb = 0; kb < 8; ++kb) {
            int off = kb*64 + G*16;
            bf16x8 af = *(bf16x8*)(sbase + C*512     + (off ^ Ck));
            bf16x8 cf = *(bf16x8*)(cbase + (C&7)*512 + (off ^ Ck));
            accg = __builtin_amdgcn_mfma_f32_16x16x32_bf16(af, af, accg, 0, 0, 0);
            acce = __builtin_amdgcn_mfma_f32_16x16x32_bf16(af, cf, acce, 0, 0, 0);
        }

        // ---- inv from Gram diag, cross-lane only ----
        // diag of row j lives on lane Ld(j) = ((j>>2)<<4)|j as accg[j&3]
        float xd = (lane&3)==0 ? accg[0] : (lane&3)==1 ? accg[1]
                 : (lane&3)==2 ? accg[2] : accg[3];
        float invv = 1.0f / (sqrtf(xd) + 1e-12f);
        float invcol = __shfl(invv, ((C >> 2) << 4) | C);

        // ---- colsum from just-staged bf16 LDS (row layout, own address) ----
        #pragma unroll
        for (int s = 0; s < 8; ++s) {
            float ia = __shfl(invv, (( s    >> 2) << 4) |  s    );
            float ib = __shfl(invv, (((s+8) >> 2) << 4) | (s+8) );
            uint2 qa = *(uint2*)(sbase +  s   *512 + ((lane*8) ^ ((s & 7) << 4)));
            uint2 qb = *(uint2*)(sbase + (s+8)*512 + ((lane*8) ^ ((s & 7) << 4)));
            colacc[s][0] += bflo(qa.x)*ia + bflo(qb.x)*ib;
            colacc[s][1] += bfhi(qa.x)*ia + bfhi(qb.x)*ib;
            colacc[s][2] += bflo(qa.y)*ia + bflo(qb.y)*ib;
            colacc[s][3] += bfhi(qa.y)*ia + bfhi(qb.y)*ib;
        }

        // ---- losses (C/D layout: col=C, row=G*4+reg) ----
        #pragma unroll
        for (int reg = 0; reg < 4; ++reg) {
            int r = G*4 + reg;
            float invr = __shfl(invv, (G << 4) | (G*4 + reg));
            float Cv = accg[reg] * invr * invcol;
            bool inblk = ((r >> 3) == (C >> 3));
            float tgt = (r == C) ? 1.0f : 0.0f;
            l1 += inblk ? fabsf(Cv - tgt) : 0.0f;

            float e  = acce[reg] * invr;
            float Dv = fmaxf(fmaf(-0.5f, e, 0.5f), 1e-12f);
            bool ond = ((C & 7) == (r & 7));
            float dmin = Dv + (ond ? 1.0f : 0.0f);
            #pragma unroll
            for (int m = 1; m < 16; m <<= 1)
                dmin = fminf(dmin, __shfl_xor(dmin, m));
            // diag lane's own Dv IS ddiag; count once (lane C = r&7)
            float sp = __logf(1.0f + __expf(Dv - dmin));
            l2 += (C == (r & 7)) ? sp : 0.0f;
        }
    }

    // ---------------- block epilogue ----------------
    #pragma unroll
    for (int m = 1; m < 64; m <<= 1) { l1 += __shfl_xor(l1, m); l2 += __shfl_xor(l2, m); }
    if (lane == 0) { lds_red[w] = l1; lds_red[4 + w] = l2; }

    // per-wave colsum -> own staging region, natural [stripe][256] layout
    float* cf = (float*)&lds_stage[w][0];
    #pragma unroll
    for (int s = 0; s < 8; ++s)
        *(f32x4*)(cf + s*256 + lane*4) = colacc[s];
    __syncthreads();

    const float* lf = (const float*)lds_stage;
    if (ATOMIC) {
        #pragma unroll
        for (int c8 = 0; c8 < 8; ++c8) {
            int idx = c8*256 + tid;
            gfadd(&ws[idx], lf[idx] + lf[2048+idx] + lf[4096+idx] + lf[6144+idx]);
        }
        if (tid == 0) {
            gfadd(&ws[2048], lds_red[0]+lds_red[1]+lds_red[2]+lds_red[3]);
            gfadd(&ws[2049], lds_red[4]+lds_red[5]+lds_red[6]+lds_red[7]);
        }
    } else {
        float* wb = ws + (size_t)blockIdx.x * 2048;
        #pragma unroll
        for (int c8 = 0; c8 < 8; ++c8) {
            int idx = c8*256 + tid;
            wb[idx] = lf[idx] + lf[2048+idx] + lf[4096+idx] + lf[6144+idx];
        }
        if (tid == 0) {
            ws[(size_t)nblk*2048 + blockIdx.x]        = lds_red[0]+lds_red[1]+lds_red[2]+lds_red[3];
            ws[(size_t)nblk*2048 + nblk + blockIdx.x] = lds_red[4]+lds_red[5]+lds_red[6]+lds_red[7];
        }
    }
}

// ---------------- finalize ----------------
// blocks 0..127: new_cc, 16 cols x 16 parallel k-chunks; block 128: loss.

template<int NB>
__global__ __launch_bounds__(256) void nssd_finalize(const float* __restrict__ ws,
                                                     const float* __restrict__ cc,
                                                     float* __restrict__ out,
                                                     int loff)
{
    __shared__ float red[256];
    const int t = threadIdx.x;
    if (blockIdx.x < 128) {
        const int col = blockIdx.x*16 + (t & 15);
        const int kc  = t >> 4;                 // 0..15
        const int chunk = (NB + 15) / 16;
        const int k0 = kc * chunk;
        const int k1 = (k0 + chunk < NB) ? (k0 + chunk) : NB;
        float s0 = 0.f, s1 = 0.f, s2 = 0.f, s3 = 0.f;
        int k = k0;
        for (; k + 4 <= k1; k += 4) {
            s0 += ws[(size_t)(k+0)*2048 + col];
            s1 += ws[(size_t)(k+1)*2048 + col];
            s2 += ws[(size_t)(k+2)*2048 + col];
            s3 += ws[(size_t)(k+3)*2048 + col];
        }
        for (; k < k1; ++k) s0 += ws[(size_t)k*2048 + col];
        red[t] = (s0 + s1) + (s2 + s3);
        __syncthreads();
        if (t < 16) {
            float v = 0.f;
            #pragma unroll
            for (int i = 0; i < 16; ++i) v += red[i*16 + t];
            int o = blockIdx.x*16 + t;
            out[1 + o] = 0.9f*cc[o] + 0.1f*(v * (1.0f/32768.0f));
        }
    } else {
        const float* lp = ws + loff;
        float s1 = 0.f, s2 = 0.f;
        for (int i = t; i < NB; i += 256) { s1 += lp[i]; s2 += lp[NB + i]; }
        #pragma unroll
        for (int m = 1; m <= 32; m <<= 1) { s1 += __shfl_xor(s1, m); s2 += __shfl_xor(s2, m); }
        if ((t & 63) == 0) { red[t >> 6] = s1; red[4 + (t >> 6)] = s2; }
        __syncthreads();
        if (t == 0) {
            float a = red[0] + red[1] + red[2] + red[3];
            float b = red[4] + red[5] + red[6] + red[7];
            out[0] = a * (1.0f/(32768.0f*64.0f)) + b * (1.0f/(32768.0f*8.0f));
        }
    }
}

// ---------------- launch ----------------

extern "C" void kernel_launch(void* const* d_in, const int* in_sizes, int n_in,
                              void* d_out, int out_size, void* d_ws, size_t ws_size,
                              hipStream_t stream)
{
    const float* gf = (const float*)d_in[0];
    const float* cc = (const float*)d_in[1];
    float* out = (float*)d_out;
    float* ws  = (float*)d_ws;

    const size_t need_store = (size_t)(NBLK*2048 + 2*NBLK) * sizeof(float);

    if (ws_size >= need_store) {
        hipLaunchKernelGGL((nssd_main<false>), dim3(NBLK), dim3(256), 0, stream,
                           gf, cc, ws, NBLK);
        hipLaunchKernelGGL((nssd_finalize<NBLK>), dim3(129), dim3(256), 0, stream,
                           ws, cc, out, NBLK*2048);
    } else {
        hipMemsetAsync(ws, 0, 2050*sizeof(float), stream);
        hipLaunchKernelGGL((nssd_main<true>), dim3(NBLK), dim3(256), 0, stream,
                           gf, cc, ws, NBLK);
        hipLaunchKernelGGL((nssd_finalize<1>), dim3(129), dim3(256), 0, stream,
                           ws, cc, out, 2048);
    }
}

// Round 14
// 62.478 us; speedup vs baseline: 2.3948x; 2.3948x over previous
//
#include <hip/hip_runtime.h>
#include <hip/hip_bf16.h>
#include <math.h>

#define N_SAMP 32768
#define NPAIR  (N_SAMP/2)
#define NBLK   768                 // 3 blocks/CU -> reg headroom (R5 lesson)

typedef short bf16x8 __attribute__((ext_vector_type(8)));
typedef float f32x4  __attribute__((ext_vector_type(4)));

__device__ __forceinline__ float dot4(const float4& a, const float4& b) {
    return a.x*b.x + a.y*b.y + a.z*b.z + a.w*b.w;
}
__device__ __forceinline__ ushort f2bfu(float x) {
    __hip_bfloat16 h = __float2bfloat16(x);
    ushort u; __builtin_memcpy(&u, &h, 2); return u;
}
__device__ __forceinline__ unsigned int pk2bf(float x, float y) {
    return (unsigned int)f2bfu(x) | ((unsigned int)f2bfu(y) << 16);
}
__device__ __forceinline__ void gfadd(float* p, float v) {
    __hip_atomic_fetch_add(p, v, __ATOMIC_RELAXED, __HIP_MEMORY_SCOPE_AGENT);
}

// ---------------- main kernel ----------------
// FINAL configuration (= R7/R10/R12, best measured: 62.5 / 63.0 / 62.8 us).
// 256 threads = 4 waves; wave owns one PAIR (16 rows x 256 cols) per iter.
// Software-pipelined: next iter's 16 NT loads issued before the loss phase.
// Lessons encoded:
//  - R6: prefetch UNCONDITIONAL (clamped address), else v[16] scratch-spills
//    (84 VGPR + 267 MB scratch WRITE signature).
//  - R8/R13: prefetch distance is pinned by colsum's f32-v[] use; BOTH
//    attempts to lengthen it (bigger colfrag regs; LDS bf16 re-read) lost --
//    one-phase-deep prefetch is this kernel's local optimum.
//  - R9: NT loads are a ~19us WIN on this read-once stream.
//  - R11: do NOT peel the tail; dead clamped prefetch rides an idle pipe.

template<bool ATOMIC>
__global__ __launch_bounds__(256, 3) void nssd_main(const float* __restrict__ gf,
                                                    const float* __restrict__ cc,
                                                    float* __restrict__ ws,
                                                    int nblk)
{
    __shared__ unsigned int lds_stage[4][2048];  // 32 KB: per-wave staging; epilogue colsum
    __shared__ unsigned int lds_ccn[1024];       // 4 KB: ccn bf16 [8][256] XOR-swizzled
    __shared__ float lds_red[8];

    const int tid  = threadIdx.x;
    const int lane = tid & 63;
    const int w    = tid >> 6;

    // ---- normalize cluster_center (f32 tmp in lds_stage) ----
    {
        float* cptr = (float*)lds_stage;
        const int l32 = tid & 31, st = tid >> 5;
        const float4* cc4 = (const float4*)cc;
        float4 a = cc4[st*64 + l32];
        float4 b = cc4[st*64 + 32 + l32];
        float ss = dot4(a,a) + dot4(b,b);
        #pragma unroll
        for (int m = 1; m < 32; m <<= 1) ss += __shfl_xor(ss, m);
        float inv = 1.0f / (sqrtf(ss) + 1e-12f);
        *(float4*)(cptr + st*256 + l32*4)       = make_float4(a.x*inv,a.y*inv,a.z*inv,a.w*inv);
        *(float4*)(cptr + st*256 + 128 + l32*4) = make_float4(b.x*inv,b.y*inv,b.z*inv,b.w*inv);
    }
    __syncthreads();
    // ---- ccn -> bf16 LDS, swizzled: byte = row*512 + ((col*2) ^ (row<<4)) ----
    {
        const float* cptr = (const float*)lds_stage;
        int row = tid >> 5, c0 = (tid & 31) * 8;
        uint4 uu;
        uu.x = pk2bf(cptr[row*256+c0+0], cptr[row*256+c0+1]);
        uu.y = pk2bf(cptr[row*256+c0+2], cptr[row*256+c0+3]);
        uu.z = pk2bf(cptr[row*256+c0+4], cptr[row*256+c0+5]);
        uu.w = pk2bf(cptr[row*256+c0+6], cptr[row*256+c0+7]);
        *(uint4*)((char*)lds_ccn + row*512 + ((c0*2) ^ (row << 4))) = uu;
    }
    __syncthreads();

    char* sbase = (char*)lds_stage + w*8192;
    char* cbase = (char*)lds_ccn;
    const int G = lane >> 4, C = lane & 15;
    const int Ck = (C & 7) << 4;

    f32x4 colacc[8];
    #pragma unroll
    for (int s = 0; s < 8; ++s) colacc[s] = (f32x4){0.f,0.f,0.f,0.f};
    float l1 = 0.f, l2 = 0.f;

    const int stride = nblk*4;
    int p = blockIdx.x*4 + w;          // always < NPAIR at start (3072 <= 16384)

    // ---- prologue: issue first tile's loads (unconditional) ----
    f32x4 v[16];
    {
        const f32x4* g4 = (const f32x4*)(gf + (size_t)p * 4096);
        #pragma unroll
        for (int i = 0; i < 16; ++i)
            v[i] = __builtin_nontemporal_load(g4 + i*64 + lane);
    }

    for (; p < NPAIR; p += stride) {
        // ---- convert + stage (swizzled) ----
        #pragma unroll
        for (int i = 0; i < 16; ++i) {
            uint2 uu = make_uint2(pk2bf(v[i][0], v[i][1]), pk2bf(v[i][2], v[i][3]));
            *(uint2*)(sbase + i*512 + ((lane*8) ^ ((i & 7) << 4))) = uu;
        }

        // ---- MFMA: Gram (u,u) and E (u,ccn), K=256 in 8 steps ----
        f32x4 accg = (f32x4){0.f,0.f,0.f,0.f};
        f32x4 acce = (f32x4){0.f,0.f,0.f,0.f};
        #pragma unroll
        for (int kb = 0; kb < 8; ++kb) {
            int off = kb*64 + G*16;
            bf16x8 af = *(bf16x8*)(sbase + C*512     + (off ^ Ck));
            bf16x8 cf = *(bf16x8*)(cbase + (C&7)*512 + (off ^ Ck));
            accg = __builtin_amdgcn_mfma_f32_16x16x32_bf16(af, af, accg, 0, 0, 0);
            acce = __builtin_amdgcn_mfma_f32_16x16x32_bf16(af, cf, acce, 0, 0, 0);
        }

        // ---- inv from Gram diag, cross-lane only ----
        // diag of row j lives on lane Ld(j) = ((j>>2)<<4)|j as accg[j&3]
        float xd = (lane&3)==0 ? accg[0] : (lane&3)==1 ? accg[1]
                 : (lane&3)==2 ? accg[2] : accg[3];
        float invv = 1.0f / (sqrtf(xd) + 1e-12f);
        float invcol = __shfl(invv, ((C >> 2) << 4) | C);

        // ---- colsum from live f32 v[] (row layout); v DIES here ----
        #pragma unroll
        for (int s = 0; s < 8; ++s) {
            float ia = __shfl(invv, (( s    >> 2) << 4) |  s    );
            float ib = __shfl(invv, (((s+8) >> 2) << 4) | (s+8) );
            colacc[s] += v[s]*ia + v[s+8]*ib;
        }

        // ---- issue NEXT tile's loads, UNCONDITIONAL via clamped address ----
        {
            int pn = p + stride;
            size_t pa = (size_t)(pn < NPAIR ? pn : 0) * 4096;
            const f32x4* g4 = (const f32x4*)(gf + pa);
            #pragma unroll
            for (int i = 0; i < 16; ++i)
                v[i] = __builtin_nontemporal_load(g4 + i*64 + lane);
        }
        __builtin_amdgcn_sched_barrier(0);   // don't sink the loads below

        // ---- losses (C/D layout: col=C, row=G*4+reg) ----
        #pragma unroll
        for (int reg = 0; reg < 4; ++reg) {
            int r = G*4 + reg;
            float invr = __shfl(invv, (G << 4) | (G*4 + reg));
            float Cv = accg[reg] * invr * invcol;
            bool inblk = ((r >> 3) == (C >> 3));
            float tgt = (r == C) ? 1.0f : 0.0f;
            l1 += inblk ? fabsf(Cv - tgt) : 0.0f;

            float e  = acce[reg] * invr;
            float Dv = fmaxf(fmaf(-0.5f, e, 0.5f), 1e-12f);
            bool ond = ((C & 7) == (r & 7));
            float dmin = Dv + (ond ? 1.0f : 0.0f);
            #pragma unroll
            for (int m = 1; m < 16; m <<= 1)
                dmin = fminf(dmin, __shfl_xor(dmin, m));
            // diag lane's own Dv IS ddiag; count once (lane C = r&7)
            float sp = __logf(1.0f + __expf(Dv - dmin));
            l2 += (C == (r & 7)) ? sp : 0.0f;
        }
    }

    // ---------------- block epilogue ----------------
    #pragma unroll
    for (int m = 1; m < 64; m <<= 1) { l1 += __shfl_xor(l1, m); l2 += __shfl_xor(l2, m); }
    if (lane == 0) { lds_red[w] = l1; lds_red[4 + w] = l2; }

    // per-wave colsum -> own staging region, natural [stripe][256] layout
    float* cf = (float*)&lds_stage[w][0];
    #pragma unroll
    for (int s = 0; s < 8; ++s)
        *(f32x4*)(cf + s*256 + lane*4) = colacc[s];
    __syncthreads();

    const float* lf = (const float*)lds_stage;
    if (ATOMIC) {
        #pragma unroll
        for (int c8 = 0; c8 < 8; ++c8) {
            int idx = c8*256 + tid;
            gfadd(&ws[idx], lf[idx] + lf[2048+idx] + lf[4096+idx] + lf[6144+idx]);
        }
        if (tid == 0) {
            gfadd(&ws[2048], lds_red[0]+lds_red[1]+lds_red[2]+lds_red[3]);
            gfadd(&ws[2049], lds_red[4]+lds_red[5]+lds_red[6]+lds_red[7]);
        }
    } else {
        float* wb = ws + (size_t)blockIdx.x * 2048;
        #pragma unroll
        for (int c8 = 0; c8 < 8; ++c8) {
            int idx = c8*256 + tid;
            wb[idx] = lf[idx] + lf[2048+idx] + lf[4096+idx] + lf[6144+idx];
        }
        if (tid == 0) {
            ws[(size_t)nblk*2048 + blockIdx.x]        = lds_red[0]+lds_red[1]+lds_red[2]+lds_red[3];
            ws[(size_t)nblk*2048 + nblk + blockIdx.x] = lds_red[4]+lds_red[5]+lds_red[6]+lds_red[7];
        }
    }
}

// ---------------- finalize ----------------
// blocks 0..127: new_cc, 16 cols x 16 parallel k-chunks; block 128: loss.

template<int NB>
__global__ __launch_bounds__(256) void nssd_finalize(const float* __restrict__ ws,
                                                     const float* __restrict__ cc,
                                                     float* __restrict__ out,
                                                     int loff)
{
    __shared__ float red[256];
    const int t = threadIdx.x;
    if (blockIdx.x < 128) {
        const int col = blockIdx.x*16 + (t & 15);
        const int kc  = t >> 4;                 // 0..15
        const int chunk = (NB + 15) / 16;
        const int k0 = kc * chunk;
        const int k1 = (k0 + chunk < NB) ? (k0 + chunk) : NB;
        float s0 = 0.f, s1 = 0.f, s2 = 0.f, s3 = 0.f;
        int k = k0;
        for (; k + 4 <= k1; k += 4) {
            s0 += ws[(size_t)(k+0)*2048 + col];
            s1 += ws[(size_t)(k+1)*2048 + col];
            s2 += ws[(size_t)(k+2)*2048 + col];
            s3 += ws[(size_t)(k+3)*2048 + col];
        }
        for (; k < k1; ++k) s0 += ws[(size_t)k*2048 + col];
        red[t] = (s0 + s1) + (s2 + s3);
        __syncthreads();
        if (t < 16) {
            float v = 0.f;
            #pragma unroll
            for (int i = 0; i < 16; ++i) v += red[i*16 + t];
            int o = blockIdx.x*16 + t;
            out[1 + o] = 0.9f*cc[o] + 0.1f*(v * (1.0f/32768.0f));
        }
    } else {
        const float* lp = ws + loff;
        float s1 = 0.f, s2 = 0.f;
        for (int i = t; i < NB; i += 256) { s1 += lp[i]; s2 += lp[NB + i]; }
        #pragma unroll
        for (int m = 1; m <= 32; m <<= 1) { s1 += __shfl_xor(s1, m); s2 += __shfl_xor(s2, m); }
        if ((t & 63) == 0) { red[t >> 6] = s1; red[4 + (t >> 6)] = s2; }
        __syncthreads();
        if (t == 0) {
            float a = red[0] + red[1] + red[2] + red[3];
            float b = red[4] + red[5] + red[6] + red[7];
            out[0] = a * (1.0f/(32768.0f*64.0f)) + b * (1.0f/(32768.0f*8.0f));
        }
    }
}

// ---------------- launch ----------------

extern "C" void kernel_launch(void* const* d_in, const int* in_sizes, int n_in,
                              void* d_out, int out_size, void* d_ws, size_t ws_size,
                              hipStream_t stream)
{
    const float* gf = (const float*)d_in[0];
    const float* cc = (const float*)d_in[1];
    float* out = (float*)d_out;
    float* ws  = (float*)d_ws;

    const size_t need_store = (size_t)(NBLK*2048 + 2*NBLK) * sizeof(float);

    if (ws_size >= need_store) {
        hipLaunchKernelGGL((nssd_main<false>), dim3(NBLK), dim3(256), 0, stream,
                           gf, cc, ws, NBLK);
        hipLaunchKernelGGL((nssd_finalize<NBLK>), dim3(129), dim3(256), 0, stream,
                           ws, cc, out, NBLK*2048);
    } else {
        hipMemsetAsync(ws, 0, 2050*sizeof(float), stream);
        hipLaunchKernelGGL((nssd_main<true>), dim3(NBLK), dim3(256), 0, stream,
                           gf, cc, ws, NBLK);
        hipLaunchKernelGGL((nssd_finalize<1>), dim3(129), dim3(256), 0, stream,
                           ws, cc, out, 2048);
    }
}